// Round 1
// baseline (172.970 us; speedup 1.0000x reference)
//
#include <hip/hip_runtime.h>
#include <hip/hip_bf16.h>
#include <stdint.h>

// Problem: X = fm_t reshaped [N=1024, D=16384] fp32.
// loss = mean_{i,j} ((sq_i + sq_j - 2*g_ij)/D)^2,  g = X X^T, sq_i = |x_i|^2.
// R7: 256x256 block tiles (4 waves x 128x128 each) -> FLOP per LDS-read byte
// doubles vs 64x64 waves; kernel flips from LDS-pipe-bound to MFMA-bound.
// Upper-triangle 256-tiles: 10 of 16; off-diag weighted x2 in the loss.
// R8: move the split-K partial buffer P out of d_in[0] into d_ws when the
// workspace is big enough (needs 66.33 MB: Xb 33.55 + sq 4K + P 32.77).
// Writing d_in[0] forces the harness to restore fm_s (64 MiB) every
// iteration inside the timed stream (~21 us); keeping d_in read-only
// should drop that. Fallback to d_in[0] if ws_size is too small.
#define N_ROWS 1024
#define KDIM   16384
#define BK     32
#define KCHUNKS (KDIM / BK)      // 512
#define SPLITS  25               // 10 tiles x 25 = 250 blocks (<= 256 CUs)

#define XB_BYTES  ((size_t)N_ROWS * KDIM * 2)           // 33,554,432
#define SQ_BYTES  ((size_t)4096)                        // 1024 floats, padded
#define P_BYTES   ((size_t)10 * SPLITS * 65536 * 2)     // 32,768,000
#define WS_NEEDED (XB_BYTES + SQ_BYTES + P_BYTES)       // 66,326,528

typedef __attribute__((ext_vector_type(8))) __bf16 bf16x8;
typedef __attribute__((ext_vector_type(8))) unsigned short ushort8;
typedef __attribute__((ext_vector_type(4))) float  f32x4;

#define GLOBAL_AS __attribute__((address_space(1)))
#define LDS_AS    __attribute__((address_space(3)))

// s_waitcnt imm: vmcnt[3:0]=bits3:0, expcnt=bits6:4, lgkmcnt=bits11:8,
// vmcnt[5:4]=bits15:14. Wait ONLY on vmcnt<=N (N<16): 0x0F70 | N.
#define WAITCNT_VM(N) __builtin_amdgcn_s_waitcnt(0x0F70 | (N))

__device__ __forceinline__ void block_barrier() {
    asm volatile("" ::: "memory");
    __builtin_amdgcn_s_barrier();   // raw: no implicit vmcnt(0) drain
    asm volatile("" ::: "memory");
}

// Upper-triangle 256-tile enumeration on the 4x4 grid.
__device__ __constant__ unsigned char T_I[10] = {0,0,0,0, 1,1,1, 2,2, 3};
__device__ __constant__ unsigned char T_J[10] = {0,1,2,3, 1,2,3, 2,3, 3};

__device__ __forceinline__ unsigned short f32_to_bf16_rne(float f) {
    unsigned int u = __float_as_uint(f);
    unsigned int lsb = (u >> 16) & 1u;
    u += 0x7fffu + lsb;
    return (unsigned short)(u >> 16);
}

// Kernel 1: fused fp32->bf16 cast of X plus fp32 row norms sq[i].
// Two blocks per row; halves combined with one fp32 atomicAdd per block.
__global__ __launch_bounds__(256) void cast_sq_kernel(
        const float* __restrict__ X, unsigned short* __restrict__ Xb,
        float* __restrict__ sq) {
    const int row = blockIdx.x >> 1;
    const int seg = blockIdx.x & 1;
    const float4* src = (const float4*)(X + (size_t)row * KDIM) + seg * 2048;
    uint2* dst = (uint2*)(Xb + (size_t)row * KDIM) + seg * 2048;
    float ss = 0.f;
#pragma unroll
    for (int c = 0; c < 8; ++c) {
        int idx = c * 256 + threadIdx.x;
        float4 v = src[idx];
        ss += v.x * v.x + v.y * v.y + v.z * v.z + v.w * v.w;
        uint2 p;
        p.x = (unsigned int)f32_to_bf16_rne(v.x) | ((unsigned int)f32_to_bf16_rne(v.y) << 16);
        p.y = (unsigned int)f32_to_bf16_rne(v.z) | ((unsigned int)f32_to_bf16_rne(v.w) << 16);
        dst[idx] = p;
    }
#pragma unroll
    for (int o = 32; o; o >>= 1) ss += __shfl_down(ss, o, 64);
    __shared__ float red[4];
    int lane = threadIdx.x & 63, wv = threadIdx.x >> 6;
    if (lane == 0) red[wv] = ss;
    __syncthreads();
    if (threadIdx.x == 0) atomicAdd(&sq[row], red[0] + red[1] + red[2] + red[3]);
}

// Kernel 2: 256x256-tile split-K bf16 Gram GEMM.
// 4 waves in a 2x2 grid, each owning 128x128 (8x8 frags of 16x16x32 ->
// 256 acc VGPRs, 1 wave/SIMD). 3-stage pipeline (32 KB/stage, 96 KB LDS,
// 1 block/CU), lead-2, raw s_barrier + s_waitcnt vmcnt(8).
// LDS per stage: A[256][32] then B[256][32]; 16B chunk j of row r at slot
// j ^ ((r>>1)&3) (conflict-free ds_read_b128).
// Split s covers k-chunks [s*512/25, (s+1)*512/25) -> 20 or 21 iters.
__global__ __launch_bounds__(256, 1) void gram_gemm_kernel(
        const unsigned short* __restrict__ Xb, unsigned short* __restrict__ P) {
    __shared__ unsigned short SH[3 * 16384];  // 3 stages x 32 KB

    const int row0 = T_I[blockIdx.x] * 256;
    const int col0 = T_J[blockIdx.x] * 256;
    const int cs = (blockIdx.y * KCHUNKS) / SPLITS;
    const int ce = ((blockIdx.y + 1) * KCHUNKS) / SPLITS;
    const int niter = ce - cs;                     // 20 or 21

    const int tid  = threadIdx.x;
    const int lane = tid & 63;
    const int wv   = tid >> 6;
    const int wm   = (wv >> 1) * 128;              // wave row offset
    const int wn   = (wv & 1) * 128;               // wave col offset
    const int lr   = lane & 15;
    const int lq   = lane >> 4;                    // k-chunk 0..3
    const int soff = (lq ^ ((lr >> 1) & 3)) * 8;   // swizzled slot (shorts)

    // staging: per stage, A = 1024 16B chunks + B = 1024; 4 A + 4 B per thread
    const unsigned short* gA[4];
    const unsigned short* gB[4];
#pragma unroll
    for (int it = 0; it < 4; ++it) {
        int c = it * 256 + tid;                    // chunk 0..1023
        int r = c >> 2;                            // row 0..255
        int js = (c & 3) ^ ((r >> 1) & 3);         // swizzled global k-chunk
        gA[it] = Xb + (size_t)(row0 + r) * KDIM + cs * BK + js * 8;
        gB[it] = Xb + (size_t)(col0 + r) * KDIM + cs * BK + js * 8;
    }

    f32x4 acc[8][8] = {};

#define STAGE(ph, kk)                                                          \
    do {                                                                       \
        unsigned short* b = &SH[(ph) * 16384];                                 \
        _Pragma("unroll")                                                      \
        for (int it = 0; it < 4; ++it) {                                       \
            int c = it * 256 + tid;                                            \
            __builtin_amdgcn_global_load_lds((GLOBAL_AS void*)(void*)(gA[it] + (kk)), \
                                             (LDS_AS void*)&b[c * 8], 16, 0, 0);      \
            __builtin_amdgcn_global_load_lds((GLOBAL_AS void*)(void*)(gB[it] + (kk)), \
                                             (LDS_AS void*)&b[8192 + c * 8], 16, 0, 0); \
        }                                                                      \
    } while (0)

#define COMPUTE(ph)                                                            \
    do {                                                                       \
        const unsigned short* b = &SH[(ph) * 16384];                           \
        bf16x8 af[8], bq[8];                                                   \
        _Pragma("unroll")                                                      \
        for (int i = 0; i < 8; ++i)                                            \
            af[i] = *(const bf16x8*)&b[(wm + i * 16 + lr) * 32 + soff];        \
        _Pragma("unroll")                                                      \
        for (int j = 0; j < 8; ++j)                                            \
            bq[j] = *(const bf16x8*)&b[8192 + (wn + j * 16 + lr) * 32 + soff]; \
        _Pragma("unroll")                                                      \
        for (int i = 0; i < 8; ++i)                                            \
            _Pragma("unroll")                                                  \
            for (int j = 0; j < 8; ++j)                                        \
                acc[i][j] = __builtin_amdgcn_mfma_f32_16x16x32_bf16(           \
                    af[i], bq[j], acc[i][j], 0, 0, 0);                         \
    } while (0)

    STAGE(0, 0);
    STAGE(1, BK);

    int cph = 0, wph = 2;
    for (int k = 0; k < niter; ++k) {
        if (k < niter - 1) WAITCNT_VM(8);   // stage k (8 oldest) landed
        else               WAITCNT_VM(0);   // last: only 8 remain, full drain
        block_barrier();
        if (k + 2 < niter) STAGE(wph, (k + 2) * BK);
        COMPUTE(cph);
        cph = (cph == 2) ? 0 : cph + 1;
        wph = (wph == 2) ? 0 : wph + 1;
    }
#undef STAGE
#undef COMPUTE

    // epilogue: bf16 partial store, P[(tile*SPLITS + split)][256*256].
    // C/D layout: col = lane&15, row = (lane>>4)*4 + reg.
    unsigned short* dst = P + ((size_t)blockIdx.x * SPLITS + blockIdx.y) * 65536;
    const int rbase = wm + lq * 4;
    const int cbase = wn + lr;
#pragma unroll
    for (int i = 0; i < 8; ++i)
#pragma unroll
        for (int j = 0; j < 8; ++j)
#pragma unroll
            for (int r = 0; r < 4; ++r) {
                int e = (rbase + i * 16 + r) * 256 + (cbase + j * 16);
                dst[e] = f32_to_bf16_rne(acc[i][j][r]);
            }
}

// Kernel 3: loss = (1/N^2) * sum over upper 256-tiles of w*((sq_i+sq_j-2g)/D)^2
// Each thread owns 8 consecutive e of one tile: 25 coalesced ushort8 loads.
// 320 blocks x 256 thr x 8 e = 10 tiles x 65536 exact.
__global__ __launch_bounds__(256) void loss_kernel(
        const unsigned short* __restrict__ P, const float* __restrict__ sq,
        float* __restrict__ out) {
    const float invD = 1.0f / (float)KDIM;
    const int u  = blockIdx.x * 256 + threadIdx.x;  // 0..81919
    const int t  = u >> 13;                         // tile 0..9
    const int e0 = (u & 8191) * 8;                  // element base in tile

    const unsigned short* pb = P + (size_t)t * SPLITS * 65536 + e0;
    float g[8] = {};
#pragma unroll
    for (int s = 0; s < SPLITS; ++s) {
        ushort8 v = *(const ushort8*)(pb + (size_t)s * 65536);
#pragma unroll
        for (int x = 0; x < 8; ++x)
            g[x] += __uint_as_float(((unsigned int)v[x]) << 16);
    }
    const int i  = T_I[t] * 256 + (e0 >> 8);
    const int jb = T_J[t] * 256 + (e0 & 255);
    const float w = (T_I[t] == T_J[t]) ? 1.0f : 2.0f;
    const float sqi = sq[i];
    float acc = 0.f;
#pragma unroll
    for (int x = 0; x < 8; ++x) {
        float v = (sqi + sq[jb + x] - 2.0f * g[x]) * invD;
        acc += w * v * v;
    }
#pragma unroll
    for (int o = 32; o; o >>= 1) acc += __shfl_down(acc, o, 64);
    __shared__ float red[4];
    int lane = threadIdx.x & 63, wv = threadIdx.x >> 6;
    if (lane == 0) red[wv] = acc;
    __syncthreads();
    if (threadIdx.x == 0) {
        float total = red[0] + red[1] + red[2] + red[3];
        atomicAdd(out, total * (1.0f / ((float)N_ROWS * (float)N_ROWS)));
    }
}

extern "C" void kernel_launch(void* const* d_in, const int* in_sizes, int n_in,
                              void* d_out, int out_size, void* d_ws, size_t ws_size,
                              hipStream_t stream) {
    const float* fm_t = (const float*)d_in[1];
    float* out = (float*)d_out;

    // Workspace layout: Xb bf16 [33.55 MB] | sq fp32 [4 KB] | P bf16 [32.77 MB]
    char* ws = (char*)d_ws;
    unsigned short* Xb = (unsigned short*)ws;
    float* sq = (float*)(ws + XB_BYTES);

    // R8: keep d_in strictly read-only when the workspace can hold P, so the
    // harness has no dirty input to restore inside the timed stream. If the
    // workspace is too small, fall back to the old scheme (d_in[0] = fm_s is
    // a dead input per the reference bug; harness restores it per launch).
    unsigned short* P = (ws_size >= WS_NEEDED)
        ? (unsigned short*)(ws + XB_BYTES + SQ_BYTES)
        : (unsigned short*)d_in[0];

    hipMemsetAsync(out, 0, sizeof(float), stream);
    hipMemsetAsync(sq, 0, N_ROWS * sizeof(float), stream);

    cast_sq_kernel<<<dim3(2 * N_ROWS), 256, 0, stream>>>(fm_t, Xb, sq);
    gram_gemm_kernel<<<dim3(10, SPLITS), 256, 0, stream>>>(Xb, P);
    loss_kernel<<<dim3(320), 256, 0, stream>>>(P, sq, out);
}

// Round 2
// 168.394 us; speedup vs baseline: 1.0272x; 1.0272x over previous
//
#include <hip/hip_runtime.h>
#include <hip/hip_bf16.h>
#include <stdint.h>

// Problem: X = fm_t reshaped [N=1024, D=16384] fp32.
// loss = mean_{i,j} ((sq_i + sq_j - 2*g_ij)/D)^2,  g = X X^T, sq_i = |x_i|^2.
// R7: 256x256 block tiles (4 waves x 128x128 each) -> MFMA-bound.
// R8: P moved to d_ws (neutral -> harness overhead is fixed ~120us).
// R9: (a) 16x16x32 -> 32x32x16 MFMA (2495 vs 2075 TF ubench ceiling, same
//     LDS traffic: 16 ds_read_b128/wave-iter either way); (b) drop both
//     hipMemsetAsync dispatches: sq becomes a 2048-slot plain-store array
//     (no atomic -> no zero-init) and out is zeroed by cast block 0.
#define N_ROWS 1024
#define KDIM   16384
#define BK     32
#define KCHUNKS (KDIM / BK)      // 512
#define SPLITS  25               // 10 tiles x 25 = 250 blocks (<= 256 CUs)

#define XB_BYTES  ((size_t)N_ROWS * KDIM * 2)           // 33,554,432
#define SQ_BYTES  ((size_t)8192)                        // 2048 floats
#define P_BYTES   ((size_t)10 * SPLITS * 65536 * 2)     // 32,768,000
#define WS_NEEDED (XB_BYTES + SQ_BYTES + P_BYTES)

typedef __attribute__((ext_vector_type(8)))  __bf16 bf16x8;
typedef __attribute__((ext_vector_type(8)))  unsigned short ushort8;
typedef __attribute__((ext_vector_type(16))) float  f32x16;

#define GLOBAL_AS __attribute__((address_space(1)))
#define LDS_AS    __attribute__((address_space(3)))

// s_waitcnt imm: vmcnt[3:0]=bits3:0, expcnt=bits6:4, lgkmcnt=bits11:8,
// vmcnt[5:4]=bits15:14. Wait ONLY on vmcnt<=N (N<16): 0x0F70 | N.
#define WAITCNT_VM(N) __builtin_amdgcn_s_waitcnt(0x0F70 | (N))

__device__ __forceinline__ void block_barrier() {
    asm volatile("" ::: "memory");
    __builtin_amdgcn_s_barrier();   // raw: no implicit vmcnt(0) drain
    asm volatile("" ::: "memory");
}

// Upper-triangle 256-tile enumeration on the 4x4 grid.
__device__ __constant__ unsigned char T_I[10] = {0,0,0,0, 1,1,1, 2,2, 3};
__device__ __constant__ unsigned char T_J[10] = {0,1,2,3, 1,2,3, 2,3, 3};

__device__ __forceinline__ unsigned short f32_to_bf16_rne(float f) {
    unsigned int u = __float_as_uint(f);
    unsigned int lsb = (u >> 16) & 1u;
    u += 0x7fffu + lsb;
    return (unsigned short)(u >> 16);
}

// Kernel 1: fused fp32->bf16 cast of X plus fp32 row-half norms.
// Two blocks per row; each block plain-stores its half-sum into sq2[bid]
// (no atomic -> no zero-init memset needed). Block 0 also zeroes out[0]
// (stream-ordered before loss_kernel's atomicAdds).
__global__ __launch_bounds__(256) void cast_sq_kernel(
        const float* __restrict__ X, unsigned short* __restrict__ Xb,
        float* __restrict__ sq2, float* __restrict__ out) {
    if (blockIdx.x == 0 && threadIdx.x == 0) out[0] = 0.f;
    const int row = blockIdx.x >> 1;
    const int seg = blockIdx.x & 1;
    const float4* src = (const float4*)(X + (size_t)row * KDIM) + seg * 2048;
    uint2* dst = (uint2*)(Xb + (size_t)row * KDIM) + seg * 2048;
    float ss = 0.f;
#pragma unroll
    for (int c = 0; c < 8; ++c) {
        int idx = c * 256 + threadIdx.x;
        float4 v = src[idx];
        ss += v.x * v.x + v.y * v.y + v.z * v.z + v.w * v.w;
        uint2 p;
        p.x = (unsigned int)f32_to_bf16_rne(v.x) | ((unsigned int)f32_to_bf16_rne(v.y) << 16);
        p.y = (unsigned int)f32_to_bf16_rne(v.z) | ((unsigned int)f32_to_bf16_rne(v.w) << 16);
        dst[idx] = p;
    }
#pragma unroll
    for (int o = 32; o; o >>= 1) ss += __shfl_down(ss, o, 64);
    __shared__ float red[4];
    int lane = threadIdx.x & 63, wv = threadIdx.x >> 6;
    if (lane == 0) red[wv] = ss;
    __syncthreads();
    if (threadIdx.x == 0) sq2[blockIdx.x] = red[0] + red[1] + red[2] + red[3];
}

// Kernel 2: 256x256-tile split-K bf16 Gram GEMM, 32x32x16 MFMA.
// 4 waves in a 2x2 grid, each owning 128x128 (4x4 frags of 32x32x16 ->
// 256 acc VGPRs, 1 wave/SIMD). 3-stage pipeline (32 KB/stage, 96 KB LDS,
// 1 block/CU), lead-2, raw s_barrier + s_waitcnt vmcnt(8).
// LDS per stage: A[256][32] then B[256][32]; 16B chunk j of row r at slot
// j ^ ((r>>1)&3) (<=2-way bank aliasing on ds_read_b128 = free, m136).
// A/B frag (32x32x16 bf16): lane l holds row/col l&31, k = (l>>5)*8 + e;
// per K=32 stage two MFMAs (k-halves s=0,1 -> chunk s*2 + (l>>5)).
// Split s covers k-chunks [s*512/25, (s+1)*512/25) -> 20 or 21 iters.
__global__ __launch_bounds__(256, 1) void gram_gemm_kernel(
        const unsigned short* __restrict__ Xb, unsigned short* __restrict__ P) {
    __shared__ unsigned short SH[3 * 16384];  // 3 stages x 32 KB

    const int row0 = T_I[blockIdx.x] * 256;
    const int col0 = T_J[blockIdx.x] * 256;
    const int cs = (blockIdx.y * KCHUNKS) / SPLITS;
    const int ce = ((blockIdx.y + 1) * KCHUNKS) / SPLITS;
    const int niter = ce - cs;                     // 20 or 21

    const int tid  = threadIdx.x;
    const int lane = tid & 63;
    const int wv   = tid >> 6;
    const int wm   = (wv >> 1) * 128;              // wave row offset
    const int wn   = (wv & 1) * 128;               // wave col offset
    const int lr   = lane & 31;                    // row/col within 32-frag
    const int lq   = lane >> 5;                    // k-subgroup 0..1

    // staging: per stage, A = 1024 16B chunks + B = 1024; 4 A + 4 B per thread
    const unsigned short* gA[4];
    const unsigned short* gB[4];
#pragma unroll
    for (int it = 0; it < 4; ++it) {
        int c = it * 256 + tid;                    // chunk 0..1023
        int r = c >> 2;                            // row 0..255
        int js = (c & 3) ^ ((r >> 1) & 3);         // swizzled global k-chunk
        gA[it] = Xb + (size_t)(row0 + r) * KDIM + cs * BK + js * 8;
        gB[it] = Xb + (size_t)(col0 + r) * KDIM + cs * BK + js * 8;
    }

    f32x16 acc[4][4] = {};

#define STAGE(ph, kk)                                                          \
    do {                                                                       \
        unsigned short* b = &SH[(ph) * 16384];                                 \
        _Pragma("unroll")                                                      \
        for (int it = 0; it < 4; ++it) {                                       \
            int c = it * 256 + tid;                                            \
            __builtin_amdgcn_global_load_lds((GLOBAL_AS void*)(void*)(gA[it] + (kk)), \
                                             (LDS_AS void*)&b[c * 8], 16, 0, 0);      \
            __builtin_amdgcn_global_load_lds((GLOBAL_AS void*)(void*)(gB[it] + (kk)), \
                                             (LDS_AS void*)&b[8192 + c * 8], 16, 0, 0); \
        }                                                                      \
    } while (0)

#define COMPUTE(ph)                                                            \
    do {                                                                       \
        const unsigned short* b = &SH[(ph) * 16384];                           \
        bf16x8 af[4][2], bq[4][2];                                             \
        _Pragma("unroll")                                                      \
        for (int i = 0; i < 4; ++i)                                            \
            _Pragma("unroll")                                                  \
            for (int s = 0; s < 2; ++s) {                                      \
                int ra = wm + i * 32 + lr;                                     \
                af[i][s] = *(const bf16x8*)&b[ra * 32 +                        \
                    ((s * 2 + lq) ^ ((ra >> 1) & 3)) * 8];                     \
            }                                                                  \
        _Pragma("unroll")                                                      \
        for (int j = 0; j < 4; ++j)                                            \
            _Pragma("unroll")                                                  \
            for (int s = 0; s < 2; ++s) {                                      \
                int rb = wn + j * 32 + lr;                                     \
                bq[j][s] = *(const bf16x8*)&b[8192 + rb * 32 +                 \
                    ((s * 2 + lq) ^ ((rb >> 1) & 3)) * 8];                     \
            }                                                                  \
        _Pragma("unroll")                                                      \
        for (int i = 0; i < 4; ++i)                                            \
            _Pragma("unroll")                                                  \
            for (int j = 0; j < 4; ++j) {                                      \
                acc[i][j] = __builtin_amdgcn_mfma_f32_32x32x16_bf16(           \
                    af[i][0], bq[j][0], acc[i][j], 0, 0, 0);                   \
                acc[i][j] = __builtin_amdgcn_mfma_f32_32x32x16_bf16(           \
                    af[i][1], bq[j][1], acc[i][j], 0, 0, 0);                   \
            }                                                                  \
    } while (0)

    STAGE(0, 0);
    STAGE(1, BK);

    int cph = 0, wph = 2;
    for (int k = 0; k < niter; ++k) {
        if (k < niter - 1) WAITCNT_VM(8);   // stage k (8 oldest) landed
        else               WAITCNT_VM(0);   // last: only 8 remain, full drain
        block_barrier();
        if (k + 2 < niter) STAGE(wph, (k + 2) * BK);
        COMPUTE(cph);
        cph = (cph == 2) ? 0 : cph + 1;
        wph = (wph == 2) ? 0 : wph + 1;
    }
#undef STAGE
#undef COMPUTE

    // epilogue: bf16 partial store, P[(tile*SPLITS + split)][256*256].
    // 32x32 C/D layout: col = lane&31, row = (t&3) + 8*(t>>2) + 4*(lane>>5).
    unsigned short* dst = P + ((size_t)blockIdx.x * SPLITS + blockIdx.y) * 65536;
    const int rq = 4 * lq;
    const int cbase = wn + lr;
#pragma unroll
    for (int i = 0; i < 4; ++i)
#pragma unroll
        for (int j = 0; j < 4; ++j)
#pragma unroll
            for (int t = 0; t < 16; ++t) {
                int row = wm + i * 32 + (t & 3) + 8 * (t >> 2) + rq;
                int e = row * 256 + (cbase + j * 32);
                dst[e] = f32_to_bf16_rne(acc[i][j][t]);
            }
}

// Kernel 3: loss = (1/N^2) * sum over upper 256-tiles of w*((sq_i+sq_j-2g)/D)^2
// Each thread owns 8 consecutive e of one tile: 25 coalesced ushort8 loads.
// 320 blocks x 256 thr x 8 e = 10 tiles x 65536 exact.
// sq comes as 2048 half-row sums: sq_i = sq2[2i] + sq2[2i+1].
__global__ __launch_bounds__(256) void loss_kernel(
        const unsigned short* __restrict__ P, const float* __restrict__ sq2,
        float* __restrict__ out) {
    const float invD = 1.0f / (float)KDIM;
    const int u  = blockIdx.x * 256 + threadIdx.x;  // 0..81919
    const int t  = u >> 13;                         // tile 0..9
    const int e0 = (u & 8191) * 8;                  // element base in tile

    const unsigned short* pb = P + (size_t)t * SPLITS * 65536 + e0;
    float g[8] = {};
#pragma unroll
    for (int s = 0; s < SPLITS; ++s) {
        ushort8 v = *(const ushort8*)(pb + (size_t)s * 65536);
#pragma unroll
        for (int x = 0; x < 8; ++x)
            g[x] += __uint_as_float(((unsigned int)v[x]) << 16);
    }
    const float2* sqp = (const float2*)sq2;
    const int i  = T_I[t] * 256 + (e0 >> 8);
    const int jb = T_J[t] * 256 + (e0 & 255);
    const float w = (T_I[t] == T_J[t]) ? 1.0f : 2.0f;
    const float2 si = sqp[i];
    const float sqi = si.x + si.y;
    float acc = 0.f;
#pragma unroll
    for (int x = 0; x < 8; ++x) {
        float2 sj = sqp[jb + x];
        float v = (sqi + (sj.x + sj.y) - 2.0f * g[x]) * invD;
        acc += w * v * v;
    }
#pragma unroll
    for (int o = 32; o; o >>= 1) acc += __shfl_down(acc, o, 64);
    __shared__ float red[4];
    int lane = threadIdx.x & 63, wv = threadIdx.x >> 6;
    if (lane == 0) red[wv] = acc;
    __syncthreads();
    if (threadIdx.x == 0) {
        float total = red[0] + red[1] + red[2] + red[3];
        atomicAdd(out, total * (1.0f / ((float)N_ROWS * (float)N_ROWS)));
    }
}

extern "C" void kernel_launch(void* const* d_in, const int* in_sizes, int n_in,
                              void* d_out, int out_size, void* d_ws, size_t ws_size,
                              hipStream_t stream) {
    const float* fm_t = (const float*)d_in[1];
    float* out = (float*)d_out;

    // Workspace layout: Xb bf16 [33.55 MB] | sq2 fp32 [8 KB] | P bf16 [32.77 MB]
    char* ws = (char*)d_ws;
    unsigned short* Xb = (unsigned short*)ws;
    float* sq2 = (float*)(ws + XB_BYTES);

    // Keep d_in strictly read-only when the workspace can hold P; fall back
    // to d_in[0] (fm_s: dead input per the reference bug, harness-restored)
    // if ws is too small.
    unsigned short* P = (ws_size >= WS_NEEDED)
        ? (unsigned short*)(ws + XB_BYTES + SQ_BYTES)
        : (unsigned short*)d_in[0];

    cast_sq_kernel<<<dim3(2 * N_ROWS), 256, 0, stream>>>(fm_t, Xb, sq2, out);
    gram_gemm_kernel<<<dim3(10, SPLITS), 256, 0, stream>>>(Xb, P);
    loss_kernel<<<dim3(320), 256, 0, stream>>>(P, sq2, out);
}

// Round 3
// 166.716 us; speedup vs baseline: 1.0375x; 1.0101x over previous
//
#include <hip/hip_runtime.h>
#include <hip/hip_bf16.h>
#include <stdint.h>

// Problem: X = fm_t reshaped [N=1024, D=16384] fp32.
// loss = mean_{i,j} ((sq_i + sq_j - 2*g_ij)/D)^2,  g = X X^T, sq_i = |x_i|^2.
// R9: 32x32x16 MFMA + no-memset launch. Profile: gram = 66us, MfmaUtil 12%,
//     Occupancy 10% (= 4 waves/CU: acc 256 + operands > 256 VGPR -> 1
//     wave/SIMD) -> latency-bound, every stall exposed.
// R10: 8-wave (512-thr) blocks, per-wave 128x64 -> acc = 128 VGPR ->
//     ~212 regs/wave -> 8 waves/CU = 2 waves/SIMD co-resident (m114
//     overlap), and 4-stage lead-3 pipeline (128 KB LDS) for 3 iters of
//     vmcnt slack. Same tile/split/swizzle/numerics as R9.
#define N_ROWS 1024
#define KDIM   16384
#define BK     32
#define KCHUNKS (KDIM / BK)      // 512
#define SPLITS  25               // 10 tiles x 25 = 250 blocks (<= 256 CUs)

#define XB_BYTES  ((size_t)N_ROWS * KDIM * 2)           // 33,554,432
#define SQ_BYTES  ((size_t)8192)                        // 2048 floats
#define P_BYTES   ((size_t)10 * SPLITS * 65536 * 2)     // 32,768,000
#define WS_NEEDED (XB_BYTES + SQ_BYTES + P_BYTES)

typedef __attribute__((ext_vector_type(8)))  __bf16 bf16x8;
typedef __attribute__((ext_vector_type(8)))  unsigned short ushort8;
typedef __attribute__((ext_vector_type(16))) float  f32x16;

#define GLOBAL_AS __attribute__((address_space(1)))
#define LDS_AS    __attribute__((address_space(3)))

// s_waitcnt imm: vmcnt[3:0]=bits3:0, expcnt=bits6:4, lgkmcnt=bits11:8,
// vmcnt[5:4]=bits15:14. Wait ONLY on vmcnt<=N (N<16): 0x0F70 | N.
#define WAITCNT_VM(N) __builtin_amdgcn_s_waitcnt(0x0F70 | (N))

__device__ __forceinline__ void block_barrier() {
    asm volatile("" ::: "memory");
    __builtin_amdgcn_s_barrier();   // raw: no implicit vmcnt(0) drain
    asm volatile("" ::: "memory");
}

// Upper-triangle 256-tile enumeration on the 4x4 grid.
__device__ __constant__ unsigned char T_I[10] = {0,0,0,0, 1,1,1, 2,2, 3};
__device__ __constant__ unsigned char T_J[10] = {0,1,2,3, 1,2,3, 2,3, 3};

__device__ __forceinline__ unsigned short f32_to_bf16_rne(float f) {
    unsigned int u = __float_as_uint(f);
    unsigned int lsb = (u >> 16) & 1u;
    u += 0x7fffu + lsb;
    return (unsigned short)(u >> 16);
}

// Kernel 1: fused fp32->bf16 cast of X plus fp32 row-half norms.
// Two blocks per row; each block plain-stores its half-sum into sq2[bid]
// (no atomic -> no zero-init memset needed). Block 0 also zeroes out[0]
// (stream-ordered before loss_kernel's atomicAdds).
__global__ __launch_bounds__(256) void cast_sq_kernel(
        const float* __restrict__ X, unsigned short* __restrict__ Xb,
        float* __restrict__ sq2, float* __restrict__ out) {
    if (blockIdx.x == 0 && threadIdx.x == 0) out[0] = 0.f;
    const int row = blockIdx.x >> 1;
    const int seg = blockIdx.x & 1;
    const float4* src = (const float4*)(X + (size_t)row * KDIM) + seg * 2048;
    uint2* dst = (uint2*)(Xb + (size_t)row * KDIM) + seg * 2048;
    float ss = 0.f;
#pragma unroll
    for (int c = 0; c < 8; ++c) {
        int idx = c * 256 + threadIdx.x;
        float4 v = src[idx];
        ss += v.x * v.x + v.y * v.y + v.z * v.z + v.w * v.w;
        uint2 p;
        p.x = (unsigned int)f32_to_bf16_rne(v.x) | ((unsigned int)f32_to_bf16_rne(v.y) << 16);
        p.y = (unsigned int)f32_to_bf16_rne(v.z) | ((unsigned int)f32_to_bf16_rne(v.w) << 16);
        dst[idx] = p;
    }
#pragma unroll
    for (int o = 32; o; o >>= 1) ss += __shfl_down(ss, o, 64);
    __shared__ float red[4];
    int lane = threadIdx.x & 63, wv = threadIdx.x >> 6;
    if (lane == 0) red[wv] = ss;
    __syncthreads();
    if (threadIdx.x == 0) sq2[blockIdx.x] = red[0] + red[1] + red[2] + red[3];
}

// Kernel 2: 256x256-tile split-K bf16 Gram GEMM, 32x32x16 MFMA, 8 waves.
// Waves in a 2x4 grid, each owning 128x64 (4x2 frags of 32x32x16 ->
// 128 acc VGPRs; ~212 total/wave -> 8 waves/CU = 2 waves/SIMD).
// 4-stage pipeline (32 KB/stage, 128 KB LDS, 1 block/CU), lead-3,
// raw s_barrier + counted s_waitcnt (8/4/0 at the tail).
// LDS per stage: A[256][32] then B[256][32]; 16B chunk j of row r at slot
// j ^ ((r>>1)&3).
// A/B frag (32x32x16 bf16): lane l holds row/col l&31, k = (l>>5)*8 + e;
// per K=32 stage two MFMAs (k-halves s=0,1 -> chunk s*2 + (l>>5)).
// Split s covers k-chunks [s*512/25, (s+1)*512/25) -> 20 or 21 iters.
__global__ __launch_bounds__(512, 2) void gram_gemm_kernel(
        const unsigned short* __restrict__ Xb, unsigned short* __restrict__ P) {
    __shared__ unsigned short SH[4 * 16384];  // 4 stages x 32 KB

    const int row0 = T_I[blockIdx.x] * 256;
    const int col0 = T_J[blockIdx.x] * 256;
    const int cs = (blockIdx.y * KCHUNKS) / SPLITS;
    const int ce = ((blockIdx.y + 1) * KCHUNKS) / SPLITS;
    const int niter = ce - cs;                     // 20 or 21

    const int tid  = threadIdx.x;
    const int lane = tid & 63;
    const int wv   = tid >> 6;                     // 0..7
    const int wm   = (wv >> 2) * 128;              // wave row offset (2 rows)
    const int wn   = (wv & 3) * 64;                // wave col offset (4 cols)
    const int lr   = lane & 31;                    // row/col within 32-frag
    const int lq   = lane >> 5;                    // k-subgroup 0..1

    // staging: per stage, A = 1024 16B chunks + B = 1024; 2 A + 2 B per thread
    const unsigned short* gA[2];
    const unsigned short* gB[2];
#pragma unroll
    for (int it = 0; it < 2; ++it) {
        int c = it * 512 + tid;                    // chunk 0..1023
        int r = c >> 2;                            // row 0..255
        int js = (c & 3) ^ ((r >> 1) & 3);         // swizzled global k-chunk
        gA[it] = Xb + (size_t)(row0 + r) * KDIM + cs * BK + js * 8;
        gB[it] = Xb + (size_t)(col0 + r) * KDIM + cs * BK + js * 8;
    }

    f32x16 acc[4][2] = {};

#define STAGE(ph, kk)                                                          \
    do {                                                                       \
        unsigned short* b = &SH[(ph) * 16384];                                 \
        _Pragma("unroll")                                                      \
        for (int it = 0; it < 2; ++it) {                                       \
            int c = it * 512 + tid;                                            \
            __builtin_amdgcn_global_load_lds((GLOBAL_AS void*)(void*)(gA[it] + (kk)), \
                                             (LDS_AS void*)&b[c * 8], 16, 0, 0);      \
            __builtin_amdgcn_global_load_lds((GLOBAL_AS void*)(void*)(gB[it] + (kk)), \
                                             (LDS_AS void*)&b[8192 + c * 8], 16, 0, 0); \
        }                                                                      \
    } while (0)

#define COMPUTE(ph)                                                            \
    do {                                                                       \
        const unsigned short* b = &SH[(ph) * 16384];                           \
        bf16x8 af[4][2], bq[2][2];                                             \
        _Pragma("unroll")                                                      \
        for (int i = 0; i < 4; ++i)                                            \
            _Pragma("unroll")                                                  \
            for (int s = 0; s < 2; ++s) {                                      \
                int ra = wm + i * 32 + lr;                                     \
                af[i][s] = *(const bf16x8*)&b[ra * 32 +                        \
                    ((s * 2 + lq) ^ ((ra >> 1) & 3)) * 8];                     \
            }                                                                  \
        _Pragma("unroll")                                                      \
        for (int j = 0; j < 2; ++j)                                            \
            _Pragma("unroll")                                                  \
            for (int s = 0; s < 2; ++s) {                                      \
                int rb = wn + j * 32 + lr;                                     \
                bq[j][s] = *(const bf16x8*)&b[8192 + rb * 32 +                 \
                    ((s * 2 + lq) ^ ((rb >> 1) & 3)) * 8];                     \
            }                                                                  \
        _Pragma("unroll")                                                      \
        for (int i = 0; i < 4; ++i)                                            \
            _Pragma("unroll")                                                  \
            for (int j = 0; j < 2; ++j) {                                      \
                acc[i][j] = __builtin_amdgcn_mfma_f32_32x32x16_bf16(           \
                    af[i][0], bq[j][0], acc[i][j], 0, 0, 0);                   \
                acc[i][j] = __builtin_amdgcn_mfma_f32_32x32x16_bf16(           \
                    af[i][1], bq[j][1], acc[i][j], 0, 0, 0);                   \
            }                                                                  \
    } while (0)

    STAGE(0, 0);
    STAGE(1, BK);
    STAGE(2, 2 * BK);

    int cph = 0, wph = 3;
    for (int k = 0; k < niter; ++k) {
        // stages in flight after stage k lands: min(2, niter-1-k) x 4 loads
        if (k < niter - 2)       WAITCNT_VM(8);
        else if (k == niter - 2) WAITCNT_VM(4);
        else                     WAITCNT_VM(0);
        block_barrier();
        if (k + 3 < niter) STAGE(wph, (k + 3) * BK);
        COMPUTE(cph);
        cph = (cph + 1) & 3;
        wph = (wph + 1) & 3;
    }
#undef STAGE
#undef COMPUTE

    // epilogue: bf16 partial store, P[(tile*SPLITS + split)][256*256].
    // 32x32 C/D layout: col = lane&31, row = (t&3) + 8*(t>>2) + 4*(lane>>5).
    unsigned short* dst = P + ((size_t)blockIdx.x * SPLITS + blockIdx.y) * 65536;
    const int rq = 4 * lq;
    const int cbase = wn + lr;
#pragma unroll
    for (int i = 0; i < 4; ++i)
#pragma unroll
        for (int j = 0; j < 2; ++j)
#pragma unroll
            for (int t = 0; t < 16; ++t) {
                int row = wm + i * 32 + (t & 3) + 8 * (t >> 2) + rq;
                int e = row * 256 + (cbase + j * 32);
                dst[e] = f32_to_bf16_rne(acc[i][j][t]);
            }
}

// Kernel 3: loss = (1/N^2) * sum over upper 256-tiles of w*((sq_i+sq_j-2g)/D)^2
// Each thread owns 8 consecutive e of one tile: 25 coalesced ushort8 loads.
// 320 blocks x 256 thr x 8 e = 10 tiles x 65536 exact.
// sq comes as 2048 half-row sums: sq_i = sq2[2i] + sq2[2i+1].
__global__ __launch_bounds__(256) void loss_kernel(
        const unsigned short* __restrict__ P, const float* __restrict__ sq2,
        float* __restrict__ out) {
    const float invD = 1.0f / (float)KDIM;
    const int u  = blockIdx.x * 256 + threadIdx.x;  // 0..81919
    const int t  = u >> 13;                         // tile 0..9
    const int e0 = (u & 8191) * 8;                  // element base in tile

    const unsigned short* pb = P + (size_t)t * SPLITS * 65536 + e0;
    float g[8] = {};
#pragma unroll
    for (int s = 0; s < SPLITS; ++s) {
        ushort8 v = *(const ushort8*)(pb + (size_t)s * 65536);
#pragma unroll
        for (int x = 0; x < 8; ++x)
            g[x] += __uint_as_float(((unsigned int)v[x]) << 16);
    }
    const float2* sqp = (const float2*)sq2;
    const int i  = T_I[t] * 256 + (e0 >> 8);
    const int jb = T_J[t] * 256 + (e0 & 255);
    const float w = (T_I[t] == T_J[t]) ? 1.0f : 2.0f;
    const float2 si = sqp[i];
    const float sqi = si.x + si.y;
    float acc = 0.f;
#pragma unroll
    for (int x = 0; x < 8; ++x) {
        float2 sj = sqp[jb + x];
        float v = (sqi + (sj.x + sj.y) - 2.0f * g[x]) * invD;
        acc += w * v * v;
    }
#pragma unroll
    for (int o = 32; o; o >>= 1) acc += __shfl_down(acc, o, 64);
    __shared__ float red[4];
    int lane = threadIdx.x & 63, wv = threadIdx.x >> 6;
    if (lane == 0) red[wv] = acc;
    __syncthreads();
    if (threadIdx.x == 0) {
        float total = red[0] + red[1] + red[2] + red[3];
        atomicAdd(out, total * (1.0f / ((float)N_ROWS * (float)N_ROWS)));
    }
}

extern "C" void kernel_launch(void* const* d_in, const int* in_sizes, int n_in,
                              void* d_out, int out_size, void* d_ws, size_t ws_size,
                              hipStream_t stream) {
    const float* fm_t = (const float*)d_in[1];
    float* out = (float*)d_out;

    // Workspace layout: Xb bf16 [33.55 MB] | sq2 fp32 [8 KB] | P bf16 [32.77 MB]
    char* ws = (char*)d_ws;
    unsigned short* Xb = (unsigned short*)ws;
    float* sq2 = (float*)(ws + XB_BYTES);

    // Keep d_in strictly read-only when the workspace can hold P; fall back
    // to d_in[0] (fm_s: dead input per the reference bug, harness-restored)
    // if ws is too small.
    unsigned short* P = (ws_size >= WS_NEEDED)
        ? (unsigned short*)(ws + XB_BYTES + SQ_BYTES)
        : (unsigned short*)d_in[0];

    cast_sq_kernel<<<dim3(2 * N_ROWS), 256, 0, stream>>>(fm_t, Xb, sq2, out);
    gram_gemm_kernel<<<dim3(10, SPLITS), 512, 0, stream>>>(Xb, P);
    loss_kernel<<<dim3(320), 256, 0, stream>>>(P, sq2, out);
}